// Round 1
// baseline (60753.229 us; speedup 1.0000x reference)
//
#include <hip/hip_runtime.h>
#include <stdint.h>
#include <math.h>

// ---------------------------------------------------------------------------
// QuantumDiffusionDreamer — round 1: correct fp32 baseline with exact JAX PRNG
//
// N=8192, F=512, H=1024, 50 steps. Per step:
//   qf = relu(x@Wq+bq); h0 = relu(qf@W01+b01); h1 = tanh(qf@W11+b11)
//   d0 = h0@W02+b02;    d1 = h1@W12+b12
//   hi = gelu(d0@Wi1[:512] + d1@Wi1[512:] + bi1); interf = hi@Wi2+bi2
//   x  = (x - (1-a)/sqrt(1-a)*denoised)/sqrt(a) + (sigma+0.1|qi|)*noise_t
// noise_t / x0 / u from JAX threefry2x32 (partitionable random-bits path).
// ---------------------------------------------------------------------------

#define PRNG_PARTITIONABLE 1   // flip to 0 -> legacy split-iota threefry path

__host__ __device__ inline void tf2x32(uint32_t k0, uint32_t k1,
                                       uint32_t x0, uint32_t x1,
                                       uint32_t& o0, uint32_t& o1) {
  uint32_t ks2 = k0 ^ k1 ^ 0x1BD11BDAu;
#define TF_R(r) { x0 += x1; x1 = (x1 << (r)) | (x1 >> (32 - (r))); x1 ^= x0; }
  x0 += k0; x1 += k1;
  TF_R(13) TF_R(15) TF_R(26) TF_R(6)
  x0 += k1;  x1 += ks2 + 1u;
  TF_R(17) TF_R(29) TF_R(16) TF_R(24)
  x0 += ks2; x1 += k0 + 2u;
  TF_R(13) TF_R(15) TF_R(26) TF_R(6)
  x0 += k0;  x1 += k1 + 3u;
  TF_R(17) TF_R(29) TF_R(16) TF_R(24)
  x0 += k1;  x1 += ks2 + 4u;
  TF_R(13) TF_R(15) TF_R(26) TF_R(6)
  x0 += ks2; x1 += k0 + 5u;
#undef TF_R
  o0 = x0; o1 = x1;
}

// XLA f32 ErfInv (Giles poly, w = -log1p(-x*x))
__device__ inline float erfinv_f32(float x) {
  float w = -log1pf(-x * x);
  float p;
  if (w < 5.0f) {
    w = w - 2.5f;
    p = 2.81022636e-08f;
    p = fmaf(p, w, 3.43273939e-07f);
    p = fmaf(p, w, -3.5233877e-06f);
    p = fmaf(p, w, -4.39150654e-06f);
    p = fmaf(p, w, 0.00021858087f);
    p = fmaf(p, w, -0.00125372503f);
    p = fmaf(p, w, -0.00417768164f);
    p = fmaf(p, w, 0.246640727f);
    p = fmaf(p, w, 1.50140941f);
  } else {
    w = sqrtf(w) - 3.0f;
    p = -0.000200214257f;
    p = fmaf(p, w, 0.000100950558f);
    p = fmaf(p, w, 0.00134934322f);
    p = fmaf(p, w, -0.00367342844f);
    p = fmaf(p, w, 0.00573950773f);
    p = fmaf(p, w, -0.0076224613f);
    p = fmaf(p, w, 0.00943887047f);
    p = fmaf(p, w, 1.00167406f);
    p = fmaf(p, w, 2.83297682f);
  }
  return p * x;
}

// random bits for flat element i of an n-element draw, per JAX threefry
__device__ inline uint32_t tf_bits(uint32_t k0, uint32_t k1, uint32_t i,
                                   uint32_t n, int partitionable) {
  uint32_t o0, o1;
  if (partitionable) {
    tf2x32(k0, k1, 0u, i, o0, o1);
    return o0 ^ o1;            // bit_width<=32 path XORs the two outputs
  } else {
    uint32_t half = n >> 1;    // n even for all our draws (scalar handled separately)
    if (i < half) { tf2x32(k0, k1, i, i + half, o0, o1); return o0; }
    else          { tf2x32(k0, k1, i - half, i, o0, o1); return o1; }
  }
}

__device__ inline float tf_normal(uint32_t k0, uint32_t k1, uint32_t i,
                                  uint32_t n, int part) {
  uint32_t bits = tf_bits(k0, k1, i, n, part);
  float f = __uint_as_float(0x3F800000u | (bits >> 9)) - 1.0f;  // [0,1)
  float u = f * 2.0f + (-0.99999994f);   // uniform(nextafter(-1,0), 1)
  u = fmaxf(-0.99999994f, u);
  return 1.41421356f * erfinv_f32(u);    // sqrt(2) as float32
}

// ---------------------------------------------------------------------------
// fp32 GEMM: C[M,N] = act(A@W + bias); A = [A0 | A1] along K (K0 + (Ktot-K0)).
// 128x128 tile, BK=16, 256 threads, 8x8 acc per thread.
// ACT: 0 none, 1 relu, 2 tanh, 3 gelu(exact)
// ---------------------------------------------------------------------------
template<int ACT>
__global__ __launch_bounds__(256)
void sgemm_kernel(const float* __restrict__ A0, const float* __restrict__ A1,
                  int K0, int Ktot,
                  const float* __restrict__ W, const float* __restrict__ bias,
                  float* __restrict__ C, int N) {
  __shared__ float As[16][128];
  __shared__ float Bs[16][128];
  const int tid = threadIdx.x;
  const int tx = tid & 15;
  const int ty = tid >> 4;
  const int row0 = blockIdx.y * 128;
  const int col0 = blockIdx.x * 128;

  float acc[8][8];
#pragma unroll
  for (int u = 0; u < 8; u++)
#pragma unroll
    for (int v = 0; v < 8; v++) acc[u][v] = 0.0f;

  for (int k0 = 0; k0 < Ktot; k0 += 16) {
    const float* Ap; int kOff, lda;
    if (k0 < K0) { Ap = A0; kOff = k0;      lda = K0; }
    else         { Ap = A1; kOff = k0 - K0; lda = Ktot - K0; }
#pragma unroll
    for (int l = 0; l < 2; l++) {
      int c = tid + 256 * l;              // 0..511
      int ar = c >> 2;                    // row in tile 0..127
      int ak = (c & 3) * 4;               // k offset 0,4,8,12
      float4 av = *(const float4*)(Ap + (size_t)(row0 + ar) * lda + kOff + ak);
      As[ak + 0][ar] = av.x; As[ak + 1][ar] = av.y;
      As[ak + 2][ar] = av.z; As[ak + 3][ar] = av.w;
      int br = c >> 5;                    // k row 0..15
      int bc = (c & 31) * 4;              // col 0..124
      *(float4*)(&Bs[br][bc]) =
          *(const float4*)(W + (size_t)(k0 + br) * N + col0 + bc);
    }
    __syncthreads();
#pragma unroll
    for (int kk = 0; kk < 16; kk++) {
      float a[8], b[8];
#pragma unroll
      for (int u = 0; u < 8; u++) a[u] = As[kk][ty * 8 + u];
#pragma unroll
      for (int v = 0; v < 8; v++) b[v] = Bs[kk][tx * 8 + v];
#pragma unroll
      for (int u = 0; u < 8; u++)
#pragma unroll
        for (int v = 0; v < 8; v++) acc[u][v] = fmaf(a[u], b[v], acc[u][v]);
    }
    __syncthreads();
  }

#pragma unroll
  for (int u = 0; u < 8; u++) {
    int r = row0 + ty * 8 + u;
    float tmp[8];
#pragma unroll
    for (int v = 0; v < 8; v++) {
      int cc = col0 + tx * 8 + v;
      float val = acc[u][v] + bias[cc];
      if (ACT == 1) val = fmaxf(val, 0.0f);
      if (ACT == 2) val = tanhf(val);
      if (ACT == 3) val = 0.5f * val * (1.0f + erff(val * 0.70710678118654752f));
      tmp[v] = val;
    }
    *(float4*)(C + (size_t)r * N + col0 + tx * 8) =
        make_float4(tmp[0], tmp[1], tmp[2], tmp[3]);
    *(float4*)(C + (size_t)r * N + col0 + tx * 8 + 4) =
        make_float4(tmp[4], tmp[5], tmp[6], tmp[7]);
  }
}

__global__ void init_normal_kernel(float* __restrict__ x, uint32_t k0,
                                   uint32_t k1, int n, int part) {
  int i = blockIdx.x * blockDim.x + threadIdx.x;
  if (i < n) x[i] = tf_normal(k0, k1, (uint32_t)i, (uint32_t)n, part);
}

__global__ void update_kernel(float* __restrict__ x,
                              const float* __restrict__ d0,
                              const float* __restrict__ d1,
                              const float* __restrict__ itf,
                              const float* __restrict__ a_amp,
                              const float* __restrict__ b_amp,
                              const float* __restrict__ ph,
                              float coh, float c1, float sqrt_alpha,
                              float sigma, int add_noise,
                              uint32_t k0, uint32_t k1, int n, int part) {
  int i = blockIdx.x * blockDim.x + threadIdx.x;
  if (i >= n) return;
  float aa = a_amp[0], bb = b_amp[0], pc = ph[0];
  float a2 = aa * aa, b2 = bb * bb, s = a2 + b2;
  float p0 = a2 / s, p1 = b2 / s;
  float qi = 2.0f * sqrtf(p0 * p1) * pc * coh;
  float den = sqrtf(p0) * d0[i] + sqrtf(p1) * d1[i] + qi * itf[i];
  float xn = (x[i] - c1 * den) / sqrt_alpha;
  if (add_noise) {
    float nz = tf_normal(k0, k1, (uint32_t)i, (uint32_t)n, part);
    xn += (sigma + 0.1f * fabsf(qi)) * nz;
  }
  x[i] = xn;
}

__global__ void final_kernel(const float* __restrict__ x,
                             const float* __restrict__ real,
                             float* __restrict__ out,
                             const float* __restrict__ a_amp,
                             const float* __restrict__ b_amp,
                             uint32_t k0, uint32_t k1, int n, int part) {
  int i = blockIdx.x * blockDim.x + threadIdx.x;
  if (i >= n) return;
  float aa = a_amp[0], bb = b_amp[0];
  float a2 = aa * aa, b2 = bb * bb;
  float p0 = a2 / (a2 + b2);
  uint32_t o0, o1;
  tf2x32(k0, k1, 0u, 0u, o0, o1);               // scalar draw: count = [0]
  uint32_t bits = part ? (o0 ^ o1) : o0;        // legacy pads to (0,0), takes out0
  float u = __uint_as_float(0x3F800000u | (bits >> 9)) - 1.0f;
  float xv = x[i];
  out[i] = (u < p0) ? (0.7f * xv + 0.3f * real[i]) : xv;
}

extern "C" void kernel_launch(void* const* d_in, const int* in_sizes, int n_in,
                              void* d_out, int out_size, void* d_ws,
                              size_t ws_size, hipStream_t stream) {
  const float* real  = (const float*)d_in[0];
  // d_in[1] = steps (=50, fixed by problem)
  const float* Wq  = (const float*)d_in[2];
  const float* bq  = (const float*)d_in[3];
  const float* W01 = (const float*)d_in[4];
  const float* b01 = (const float*)d_in[5];
  const float* W02 = (const float*)d_in[6];
  const float* b02 = (const float*)d_in[7];
  const float* W11 = (const float*)d_in[8];
  const float* b11 = (const float*)d_in[9];
  const float* W12 = (const float*)d_in[10];
  const float* b12 = (const float*)d_in[11];
  const float* Wi1 = (const float*)d_in[12];
  const float* bi1 = (const float*)d_in[13];
  const float* Wi2 = (const float*)d_in[14];
  const float* bi2 = (const float*)d_in[15];
  const float* a_amp = (const float*)d_in[16];
  const float* b_amp = (const float*)d_in[17];
  const float* ph    = (const float*)d_in[18];

  const int Nn = 8192, F = 512, H = 1024;
  const int part = PRNG_PARTITIONABLE;
  const int nElem = Nn * F;  // 4,194,304

  // workspace layout (fp32): ~151 MB total
  float* ws = (float*)d_ws;
  float* x  = ws;                       // [8192,512]
  float* qf = x  + (size_t)Nn * F;      // [8192,1024]  (reused as hi)
  float* h0 = qf + (size_t)Nn * H;      // [8192,1024]  (reused as interf)
  float* h1 = h0 + (size_t)Nn * H;      // [8192,1024]
  float* d0 = h1 + (size_t)Nn * H;      // [8192,512]
  float* d1 = d0 + (size_t)Nn * F;      // [8192,512]

  // x0 = normal(fold_in(key(1), 10000), (8192,512))
  uint32_t kx0, kx1; tf2x32(0u, 1u, 0u, 10000u, kx0, kx1);
  init_normal_kernel<<<(nElem + 255) / 256, 256, 0, stream>>>(x, kx0, kx1,
                                                              nElem, part);

  float sched[100];
  for (int i = 0; i < 100; i++)
    sched[i] = (float)(1e-4 + (0.02 - 1e-4) * (double)i / 99.0);
  const float decay = expf(-0.1f);
  float coh = 1.0f;

  dim3 blk(256);
  dim3 gH(H / 128, Nn / 128);  // N=1024 GEMMs
  dim3 gF(F / 128, Nn / 128);  // N=512 GEMMs

  for (int j = 0; j < 50; j++) {
    int t = 49 - j;
    // qf = relu(x @ Wq + bq)
    sgemm_kernel<1><<<gH, blk, 0, stream>>>(x, x, F, F, Wq, bq, qf, H);
    // h0 = relu(qf @ W01 + b01); h1 = tanh(qf @ W11 + b11)
    sgemm_kernel<1><<<gH, blk, 0, stream>>>(qf, qf, H, H, W01, b01, h0, H);
    sgemm_kernel<2><<<gH, blk, 0, stream>>>(qf, qf, H, H, W11, b11, h1, H);
    // d0 = h0 @ W02 + b02; d1 = h1 @ W12 + b12
    sgemm_kernel<0><<<gF, blk, 0, stream>>>(h0, h0, H, H, W02, b02, d0, F);
    sgemm_kernel<0><<<gF, blk, 0, stream>>>(h1, h1, H, H, W12, b12, d1, F);
    // hi(=qf) = gelu([d0|d1] @ Wi1 + bi1)
    sgemm_kernel<3><<<gH, blk, 0, stream>>>(d0, d1, F, 2 * F, Wi1, bi1, qf, H);
    // interf(=h0) = hi @ Wi2 + bi2
    sgemm_kernel<0><<<gF, blk, 0, stream>>>(qf, qf, H, H, Wi2, bi2, h0, F);

    // step scalars (mirror fp32 ops of the reference)
    float schedt = sched[t];
    float alphaf = fmaxf(1.0f - schedt, 1e-8f);
    float one_m_alpha = 1.0f - alphaf;
    float sqrt_1ma = sqrtf(fmaxf(one_m_alpha, 1e-8f));
    float c1 = one_m_alpha / sqrt_1ma;
    float sqa = sqrtf(alphaf);
    float sigma = 0.0f;
    if (t > 0) {
      float ap = 1.0f - sched[t - 1];
      sigma = sqrtf(fmaxf((1.0f - ap) / one_m_alpha * (1.0f - alphaf / ap), 0.0f));
    }
    uint32_t kt0, kt1; tf2x32(0u, 1u, 0u, (uint32_t)t, kt0, kt1);
    update_kernel<<<(nElem + 255) / 256, 256, 0, stream>>>(
        x, d0, d1, h0, a_amp, b_amp, ph, coh, c1, sqa, sigma, (t > 0) ? 1 : 0,
        kt0, kt1, nElem, part);
    coh *= decay;
  }

  // dream = (u < p0) ? 0.7*x + 0.3*real : x,  u = uniform(fold_in(key,99999))
  uint32_t ku0, ku1; tf2x32(0u, 1u, 0u, 99999u, ku0, ku1);
  final_kernel<<<(nElem + 255) / 256, 256, 0, stream>>>(
      x, real, (float*)d_out, a_amp, b_amp, ku0, ku1, nElem, part);
}

// Round 2
// 11724.724 us; speedup vs baseline: 5.1816x; 5.1816x over previous
//
#include <hip/hip_runtime.h>
#include <stdint.h>
#include <math.h>

// ---------------------------------------------------------------------------
// QuantumDiffusionDreamer — round 2: bf16 MFMA GEMMs (m97 structure)
// x kept fp32; activations bf16; weights transposed to [N,K] bf16 per launch.
// PRNG: JAX threefry2x32, partitionable random-bits path (verified round 1).
// ---------------------------------------------------------------------------

typedef __bf16 bf16x8 __attribute__((ext_vector_type(8)));
typedef float floatx4 __attribute__((ext_vector_type(4)));

__host__ __device__ inline void tf2x32(uint32_t k0, uint32_t k1,
                                       uint32_t x0, uint32_t x1,
                                       uint32_t& o0, uint32_t& o1) {
  uint32_t ks2 = k0 ^ k1 ^ 0x1BD11BDAu;
#define TF_R(r) { x0 += x1; x1 = (x1 << (r)) | (x1 >> (32 - (r))); x1 ^= x0; }
  x0 += k0; x1 += k1;
  TF_R(13) TF_R(15) TF_R(26) TF_R(6)
  x0 += k1;  x1 += ks2 + 1u;
  TF_R(17) TF_R(29) TF_R(16) TF_R(24)
  x0 += ks2; x1 += k0 + 2u;
  TF_R(13) TF_R(15) TF_R(26) TF_R(6)
  x0 += k0;  x1 += k1 + 3u;
  TF_R(17) TF_R(29) TF_R(16) TF_R(24)
  x0 += k1;  x1 += ks2 + 4u;
  TF_R(13) TF_R(15) TF_R(26) TF_R(6)
  x0 += ks2; x1 += k0 + 5u;
#undef TF_R
  o0 = x0; o1 = x1;
}

__device__ inline float erfinv_f32(float x) {
  float w = -log1pf(-x * x);
  float p;
  if (w < 5.0f) {
    w = w - 2.5f;
    p = 2.81022636e-08f;
    p = fmaf(p, w, 3.43273939e-07f);
    p = fmaf(p, w, -3.5233877e-06f);
    p = fmaf(p, w, -4.39150654e-06f);
    p = fmaf(p, w, 0.00021858087f);
    p = fmaf(p, w, -0.00125372503f);
    p = fmaf(p, w, -0.00417768164f);
    p = fmaf(p, w, 0.246640727f);
    p = fmaf(p, w, 1.50140941f);
  } else {
    w = sqrtf(w) - 3.0f;
    p = -0.000200214257f;
    p = fmaf(p, w, 0.000100950558f);
    p = fmaf(p, w, 0.00134934322f);
    p = fmaf(p, w, -0.00367342844f);
    p = fmaf(p, w, 0.00573950773f);
    p = fmaf(p, w, -0.0076224613f);
    p = fmaf(p, w, 0.00943887047f);
    p = fmaf(p, w, 1.00167406f);
    p = fmaf(p, w, 2.83297682f);
  }
  return p * x;
}

__device__ inline float tf_normal(uint32_t k0, uint32_t k1, uint32_t i) {
  uint32_t o0, o1;
  tf2x32(k0, k1, 0u, i, o0, o1);
  uint32_t bits = o0 ^ o1;  // partitionable random_bits path
  float f = __uint_as_float(0x3F800000u | (bits >> 9)) - 1.0f;  // [0,1)
  float u = f * 2.0f + (-0.99999994f);
  u = fmaxf(-0.99999994f, u);
  return 1.41421356f * erfinv_f32(u);
}

__device__ inline unsigned short f2bf(float f) {
  uint32_t u = __float_as_uint(f);
  u += 0x7FFFu + ((u >> 16) & 1u);   // round-to-nearest-even
  return (unsigned short)(u >> 16);
}
__device__ inline float bf2f(unsigned short h) {
  return __uint_as_float(((uint32_t)h) << 16);
}

// ---------------------------------------------------------------------------
// Weight transpose + bf16 convert: Wt[n][k] = bf16(W[k][n]);  W is [K,N] fp32.
// ---------------------------------------------------------------------------
__global__ __launch_bounds__(256)
void transpose_bf16_kernel(const float* __restrict__ W,
                           unsigned short* __restrict__ Wt, int K, int N) {
  __shared__ float tile[32][33];
  int kb = blockIdx.x * 32, nb = blockIdx.y * 32;
  int tx = threadIdx.x & 31, ty = threadIdx.x >> 5;  // ty 0..7
#pragma unroll
  for (int i = 0; i < 32; i += 8)
    tile[ty + i][tx] = W[(size_t)(kb + ty + i) * N + nb + tx];
  __syncthreads();
#pragma unroll
  for (int i = 0; i < 32; i += 8)
    Wt[(size_t)(nb + ty + i) * K + kb + tx] = f2bf(tile[tx][ty + i]);
}

// ---------------------------------------------------------------------------
// bf16 MFMA GEMM (m97 structure):
//   C[M,N] = act(A @ B + bias),  A = [A0 | A1] along K (K0 + (Ktot-K0)),
//   Bt is B transposed: [N][Ktot] bf16 row-major.
// 128x128 tile, BK=32, 256 threads = 4 waves (2x2 of 64x64), 16x16x32 MFMA.
// global_load_lds(16B) staging; LDS layout contiguous in lane order (no pad).
// ACT: 0 none, 1 relu, 2 tanh, 3 gelu(exact erf)
// ---------------------------------------------------------------------------
template<int ACT>
__global__ __launch_bounds__(256)
void mfma_gemm(const unsigned short* __restrict__ A0,
               const unsigned short* __restrict__ A1, int K0, int Ktot,
               const unsigned short* __restrict__ Bt,
               const float* __restrict__ bias,
               unsigned short* __restrict__ C, int N) {
  __shared__ unsigned short As[128 * 32];
  __shared__ unsigned short Bs[128 * 32];
  const int tid = threadIdx.x;
  const int wave = tid >> 6, lane = tid & 63;
  const int row0 = blockIdx.y * 128, col0 = blockIdx.x * 128;
  const int wr = wave >> 1, wc = wave & 1;   // wave's 64x64 quadrant

  floatx4 acc[4][4];
#pragma unroll
  for (int u = 0; u < 4; u++)
#pragma unroll
    for (int v = 0; v < 4; v++) acc[u][v] = (floatx4){0.f, 0.f, 0.f, 0.f};

  const int lrow = lane >> 2;       // 0..15
  const int lk = (lane & 3) * 8;    // 0,8,16,24 (bf16 elems; 16B granules)
  const int fm = lane & 15, quad = lane >> 4;

  for (int k0 = 0; k0 < Ktot; k0 += 32) {
    const unsigned short* Ap; int kOff, lda;
    if (k0 < K0) { Ap = A0; kOff = k0; lda = K0; }
    else         { Ap = A1; kOff = k0 - K0; lda = Ktot - K0; }
#pragma unroll
    for (int r = 0; r < 2; r++) {
      int srow = r * 64 + wave * 16 + lrow;   // 0..127, lane-contiguous LDS
      __builtin_amdgcn_global_load_lds(
          (const __attribute__((address_space(1))) uint32_t*)
              (Ap + (size_t)(row0 + srow) * lda + kOff + lk),
          (__attribute__((address_space(3))) uint32_t*)(As + srow * 32 + lk),
          16, 0, 0);
      __builtin_amdgcn_global_load_lds(
          (const __attribute__((address_space(1))) uint32_t*)
              (Bt + (size_t)(col0 + srow) * Ktot + k0 + lk),
          (__attribute__((address_space(3))) uint32_t*)(Bs + srow * 32 + lk),
          16, 0, 0);
    }
    __syncthreads();

    bf16x8 a[4], b[4];
#pragma unroll
    for (int u = 0; u < 4; u++)
      a[u] = *(const bf16x8*)(As + (wr * 64 + u * 16 + fm) * 32 + quad * 8);
#pragma unroll
    for (int v = 0; v < 4; v++)
      b[v] = *(const bf16x8*)(Bs + (wc * 64 + v * 16 + fm) * 32 + quad * 8);
#pragma unroll
    for (int u = 0; u < 4; u++)
#pragma unroll
      for (int v = 0; v < 4; v++)
        acc[u][v] = __builtin_amdgcn_mfma_f32_16x16x32_bf16(a[u], b[v],
                                                            acc[u][v], 0, 0, 0);
    __syncthreads();
  }

  // epilogue: D lane mapping col=lane&15, row=quad*4+reg (m89-verified)
#pragma unroll
  for (int v = 0; v < 4; v++) {
    int col = col0 + wc * 64 + v * 16 + fm;
    float bv = bias[col];
#pragma unroll
    for (int u = 0; u < 4; u++) {
      int rbase = row0 + wr * 64 + u * 16 + quad * 4;
#pragma unroll
      for (int r = 0; r < 4; r++) {
        float val = acc[u][v][r] + bv;
        if (ACT == 1) val = fmaxf(val, 0.0f);
        if (ACT == 2) val = tanhf(val);
        if (ACT == 3) val = 0.5f * val * (1.0f + erff(val * 0.70710678118654752f));
        C[(size_t)(rbase + r) * N + col] = f2bf(val);
      }
    }
  }
}

__global__ void init_normal_kernel(float* __restrict__ x,
                                   unsigned short* __restrict__ xbf,
                                   uint32_t k0, uint32_t k1, int n) {
  int i = blockIdx.x * blockDim.x + threadIdx.x;
  if (i >= n) return;
  float v = tf_normal(k0, k1, (uint32_t)i);
  x[i] = v;
  xbf[i] = f2bf(v);
}

__global__ void update_kernel(float* __restrict__ x,
                              unsigned short* __restrict__ xbf,
                              const unsigned short* __restrict__ d0,
                              const unsigned short* __restrict__ d1,
                              const unsigned short* __restrict__ itf,
                              const float* __restrict__ a_amp,
                              const float* __restrict__ b_amp,
                              const float* __restrict__ ph,
                              float coh, float c1, float sqrt_alpha,
                              float sigma, int add_noise,
                              uint32_t k0, uint32_t k1, int n) {
  int i = blockIdx.x * blockDim.x + threadIdx.x;
  if (i >= n) return;
  float aa = a_amp[0], bb = b_amp[0], pc = ph[0];
  float a2 = aa * aa, b2 = bb * bb, s = a2 + b2;
  float p0 = a2 / s, p1 = b2 / s;
  float qi = 2.0f * sqrtf(p0 * p1) * pc * coh;
  float den = sqrtf(p0) * bf2f(d0[i]) + sqrtf(p1) * bf2f(d1[i])
            + qi * bf2f(itf[i]);
  float xn = (x[i] - c1 * den) / sqrt_alpha;
  if (add_noise) {
    float nz = tf_normal(k0, k1, (uint32_t)i);
    xn += (sigma + 0.1f * fabsf(qi)) * nz;
  }
  x[i] = xn;
  xbf[i] = f2bf(xn);
}

__global__ void final_kernel(const float* __restrict__ x,
                             const float* __restrict__ real,
                             float* __restrict__ out,
                             const float* __restrict__ a_amp,
                             const float* __restrict__ b_amp,
                             uint32_t k0, uint32_t k1, int n) {
  int i = blockIdx.x * blockDim.x + threadIdx.x;
  if (i >= n) return;
  float aa = a_amp[0], bb = b_amp[0];
  float a2 = aa * aa, b2 = bb * bb;
  float p0 = a2 / (a2 + b2);
  uint32_t o0, o1;
  tf2x32(k0, k1, 0u, 0u, o0, o1);
  uint32_t bits = o0 ^ o1;
  float u = __uint_as_float(0x3F800000u | (bits >> 9)) - 1.0f;
  float xv = x[i];
  out[i] = (u < p0) ? (0.7f * xv + 0.3f * real[i]) : xv;
}

extern "C" void kernel_launch(void* const* d_in, const int* in_sizes, int n_in,
                              void* d_out, int out_size, void* d_ws,
                              size_t ws_size, hipStream_t stream) {
  const float* real = (const float*)d_in[0];
  const float* Wq  = (const float*)d_in[2];
  const float* bq  = (const float*)d_in[3];
  const float* W01 = (const float*)d_in[4];
  const float* b01 = (const float*)d_in[5];
  const float* W02 = (const float*)d_in[6];
  const float* b02 = (const float*)d_in[7];
  const float* W11 = (const float*)d_in[8];
  const float* b11 = (const float*)d_in[9];
  const float* W12 = (const float*)d_in[10];
  const float* b12 = (const float*)d_in[11];
  const float* Wi1 = (const float*)d_in[12];
  const float* bi1 = (const float*)d_in[13];
  const float* Wi2 = (const float*)d_in[14];
  const float* bi2 = (const float*)d_in[15];
  const float* a_amp = (const float*)d_in[16];
  const float* b_amp = (const float*)d_in[17];
  const float* ph    = (const float*)d_in[18];

  const int Nn = 8192, F = 512, H = 1024;
  const int nElem = Nn * F;  // 4,194,304

  // workspace layout
  char* ws = (char*)d_ws;
  float* x = (float*)ws;                                   ws += (size_t)nElem * 4;
  unsigned short* xbf = (unsigned short*)ws;               ws += (size_t)nElem * 2;
  unsigned short* qf  = (unsigned short*)ws;               ws += (size_t)Nn * H * 2;
  unsigned short* h0  = (unsigned short*)ws;               ws += (size_t)Nn * H * 2;
  unsigned short* h1  = (unsigned short*)ws;               ws += (size_t)Nn * H * 2;
  unsigned short* d0  = (unsigned short*)ws;               ws += (size_t)nElem * 2;
  unsigned short* d1  = (unsigned short*)ws;               ws += (size_t)nElem * 2;
  unsigned short* itf = (unsigned short*)ws;               ws += (size_t)nElem * 2;
  unsigned short* Wq_t  = (unsigned short*)ws;             ws += (size_t)F * H * 2;
  unsigned short* W01_t = (unsigned short*)ws;             ws += (size_t)H * H * 2;
  unsigned short* W11_t = (unsigned short*)ws;             ws += (size_t)H * H * 2;
  unsigned short* W02_t = (unsigned short*)ws;             ws += (size_t)H * F * 2;
  unsigned short* W12_t = (unsigned short*)ws;             ws += (size_t)H * F * 2;
  unsigned short* Wi1_t = (unsigned short*)ws;             ws += (size_t)(2 * F) * H * 2;
  unsigned short* Wi2_t = (unsigned short*)ws;             ws += (size_t)H * F * 2;

  // transpose+convert weights (per launch; graph-capture safe)
  dim3 tb(256);
  transpose_bf16_kernel<<<dim3(F / 32, H / 32), tb, 0, stream>>>(Wq, Wq_t, F, H);
  transpose_bf16_kernel<<<dim3(H / 32, H / 32), tb, 0, stream>>>(W01, W01_t, H, H);
  transpose_bf16_kernel<<<dim3(H / 32, H / 32), tb, 0, stream>>>(W11, W11_t, H, H);
  transpose_bf16_kernel<<<dim3(H / 32, F / 32), tb, 0, stream>>>(W02, W02_t, H, F);
  transpose_bf16_kernel<<<dim3(H / 32, F / 32), tb, 0, stream>>>(W12, W12_t, H, F);
  transpose_bf16_kernel<<<dim3(2 * F / 32, H / 32), tb, 0, stream>>>(Wi1, Wi1_t, 2 * F, H);
  transpose_bf16_kernel<<<dim3(H / 32, F / 32), tb, 0, stream>>>(Wi2, Wi2_t, H, F);

  uint32_t kx0, kx1; tf2x32(0u, 1u, 0u, 10000u, kx0, kx1);
  init_normal_kernel<<<(nElem + 255) / 256, 256, 0, stream>>>(x, xbf, kx0, kx1, nElem);

  float sched[100];
  for (int i = 0; i < 100; i++)
    sched[i] = (float)(1e-4 + (0.02 - 1e-4) * (double)i / 99.0);
  const float decay = expf(-0.1f);
  float coh = 1.0f;

  dim3 blk(256);
  dim3 gH(H / 128, Nn / 128);  // 512 blocks (N=1024 outputs)
  dim3 gF(F / 128, Nn / 128);  // 256 blocks (N=512 outputs)

  for (int j = 0; j < 50; j++) {
    int t = 49 - j;
    // qf = relu(x @ Wq + bq)
    mfma_gemm<1><<<gH, blk, 0, stream>>>(xbf, xbf, F, F, Wq_t, bq, qf, H);
    // h0 = relu(qf @ W01 + b01); h1 = tanh(qf @ W11 + b11)
    mfma_gemm<1><<<gH, blk, 0, stream>>>(qf, qf, H, H, W01_t, b01, h0, H);
    mfma_gemm<2><<<gH, blk, 0, stream>>>(qf, qf, H, H, W11_t, b11, h1, H);
    // d0 = h0 @ W02 + b02; d1 = h1 @ W12 + b12
    mfma_gemm<0><<<gF, blk, 0, stream>>>(h0, h0, H, H, W02_t, b02, d0, F);
    mfma_gemm<0><<<gF, blk, 0, stream>>>(h1, h1, H, H, W12_t, b12, d1, F);
    // qf (reused) = gelu([d0|d1] @ Wi1 + bi1)
    mfma_gemm<3><<<gH, blk, 0, stream>>>(d0, d1, F, 2 * F, Wi1_t, bi1, qf, H);
    // itf = qf @ Wi2 + bi2
    mfma_gemm<0><<<gF, blk, 0, stream>>>(qf, qf, H, H, Wi2_t, bi2, itf, F);

    float schedt = sched[t];
    float alphaf = fmaxf(1.0f - schedt, 1e-8f);
    float one_m_alpha = 1.0f - alphaf;
    float sqrt_1ma = sqrtf(fmaxf(one_m_alpha, 1e-8f));
    float c1 = one_m_alpha / sqrt_1ma;
    float sqa = sqrtf(alphaf);
    float sigma = 0.0f;
    if (t > 0) {
      float ap = 1.0f - sched[t - 1];
      sigma = sqrtf(fmaxf((1.0f - ap) / one_m_alpha * (1.0f - alphaf / ap), 0.0f));
    }
    uint32_t kt0, kt1; tf2x32(0u, 1u, 0u, (uint32_t)t, kt0, kt1);
    update_kernel<<<(nElem + 255) / 256, 256, 0, stream>>>(
        x, xbf, d0, d1, itf, a_amp, b_amp, ph, coh, c1, sqa, sigma,
        (t > 0) ? 1 : 0, kt0, kt1, nElem);
    coh *= decay;
  }

  uint32_t ku0, ku1; tf2x32(0u, 1u, 0u, 99999u, ku0, ku1);
  final_kernel<<<(nElem + 255) / 256, 256, 0, stream>>>(
      x, real, (float*)d_out, a_amp, b_amp, ku0, ku1, nElem);
}